// Round 12
// baseline (51.116 us; speedup 1.0000x reference)
//
#include <hip/hip_runtime.h>

// PhraseModel: two VQ argmins (z, z_pre vs codebook) + phrase gather + sum.
// Round 12: 5-BARRIER single kernel. Whole codebook as bf16 in LDS (128KB)
// -> no chunk loop (r5-r11 had ~21 barrier phases; latency-bound at ~1us+
// per phase). Plain-bf16 MFMA ranking (d2 err sigma ~0.07) + exact-f32
// top-4 refinement per row (true argmin in approx top-4 with huge margin;
// refine decides exactly -> same correctness structure as proven top-2).
// cnorm exact f32, computed during staging. Gather fused (r10-verbatim).

#define BHALF 4096
#define D 510
#define GRID 512                  // 8 output rows per block

using f32x4  = __attribute__((ext_vector_type(4))) float;
using bf16x8 = __attribute__((ext_vector_type(8))) short;

__device__ __forceinline__ unsigned short f2bf(float f) {
    union { float f; unsigned int u; } v; v.f = f;
    return (unsigned short)((v.u + 0x7FFFu + ((v.u >> 16) & 1u)) >> 16); // RTNE
}
__device__ __forceinline__ bool lexlt(float va, int ia, float vb, int ib) {
    return va < vb || (va == vb && ia < ib);
}
#define MFMA16 __builtin_amdgcn_mfma_f32_16x16x32_bf16

// LDS layout (bytes):
//   cb   @0      : 128 codes x 1024B (512 bf16, byte off (k*2)^((code&7)<<4))
//   z    @131072 : 16 rows  x 1024B (same swizzle by row)
//   cn   @147456 : 128 f32 (exact)
//   twv  @147968 : [8 waves][16 rows][4] f32   (wave-local top-4 values)
//   twi  @150016 : [8][16][4] int              (indices)
//   kb2  @152064 : [16][4] int  (global top-4 per row)
//   refd @152320 : [64] f32     (exact d2 of candidates)
//   kbf  @152576 : [16] int     (final winner per row)
#define LCB   0
#define LZ    131072
#define LCN   147456
#define LTWV  147968
#define LTWI  150016
#define LKB2  152064
#define LREFD 152320
#define LKBF  152576
#define LDSZ  152640

__launch_bounds__(512)
__global__ void fused_kernel(const float* __restrict__ z,
                             const float* __restrict__ zp,
                             const float* __restrict__ cb,
                             const float* __restrict__ ph,
                             const int* __restrict__ pos,
                             float* __restrict__ out) {
    __shared__ __align__(1024) char lds[LDSZ];

    const int tid  = threadIdx.x;
    const int lane = tid & 63;
    const int wu   = __builtin_amdgcn_readfirstlane(tid >> 6); // 0..7
    const int l15  = lane & 15;
    const int kq   = lane >> 4;          // 0..3
    const int r0   = blockIdx.x * 8;     // first output row

    float* cnL = (float*)(lds + LCN);

    // ---- stage cb: thread -> (code=tid>>2, 128-k segment), exact cn ----
    {
        const int ct    = tid >> 2;            // 0..127
        const int kbase = (tid & 3) * 128;     // 0,128,256,384
        const int cswz  = (ct & 7) << 4;
        const float* cg = cb + (size_t)ct * D;
        char* cbase = lds + LCB + ct * 1024;
        float sq = 0.f;
        #pragma unroll
        for (int g = 0; g < 8; ++g) {          // 16 k per iter
            const int k0 = kbase + g * 16;
            float v[16];
            #pragma unroll
            for (int p = 0; p < 8; ++p) {
                const int col = k0 + 2 * p;
                const float2 t2 = (col < D) ? *(const float2*)(cg + col)
                                            : make_float2(0.f, 0.f);
                v[2 * p] = t2.x; v[2 * p + 1] = t2.y;
            }
            unsigned short h[16];
            #pragma unroll
            for (int j = 0; j < 16; ++j) {
                sq = fmaf(v[j], v[j], sq);
                h[j] = f2bf(v[j]);
            }
            uint4 H0 = make_uint4((unsigned)h[0]|((unsigned)h[1]<<16),
                                  (unsigned)h[2]|((unsigned)h[3]<<16),
                                  (unsigned)h[4]|((unsigned)h[5]<<16),
                                  (unsigned)h[6]|((unsigned)h[7]<<16));
            uint4 H1 = make_uint4((unsigned)h[8]|((unsigned)h[9]<<16),
                                  (unsigned)h[10]|((unsigned)h[11]<<16),
                                  (unsigned)h[12]|((unsigned)h[13]<<16),
                                  (unsigned)h[14]|((unsigned)h[15]<<16));
            *(uint4*)(cbase + ((k0 * 2) ^ cswz))      = H0;
            *(uint4*)(cbase + ((k0 * 2 + 16) ^ cswz)) = H1;
        }
        sq += __shfl_xor(sq, 1, 64);
        sq += __shfl_xor(sq, 2, 64);
        if ((tid & 3) == 0) cnL[ct] = sq;      // exact f32 ||c||^2
    }

    // ---- stage z: thread -> (row=tid>>5, 16-k segment) ----
    {
        const int row  = tid >> 5;             // 0..15 (0-7 z, 8-15 zp)
        const int k0   = (tid & 31) * 16;      // 0..496
        const int rswz = (row & 7) << 4;
        const float* src = (row < 8) ? z + (size_t)(r0 + row) * D
                                     : zp + (size_t)(r0 + row - 8) * D;
        float v[16];
        #pragma unroll
        for (int p = 0; p < 8; ++p) {
            const int col = k0 + 2 * p;
            const float2 t2 = (col < D) ? *(const float2*)(src + col)
                                        : make_float2(0.f, 0.f);
            v[2 * p] = t2.x; v[2 * p + 1] = t2.y;
        }
        unsigned short h[16];
        #pragma unroll
        for (int j = 0; j < 16; ++j) h[j] = f2bf(v[j]);
        uint4 H0 = make_uint4((unsigned)h[0]|((unsigned)h[1]<<16),
                              (unsigned)h[2]|((unsigned)h[3]<<16),
                              (unsigned)h[4]|((unsigned)h[5]<<16),
                              (unsigned)h[6]|((unsigned)h[7]<<16));
        uint4 H1 = make_uint4((unsigned)h[8]|((unsigned)h[9]<<16),
                              (unsigned)h[10]|((unsigned)h[11]<<16),
                              (unsigned)h[12]|((unsigned)h[13]<<16),
                              (unsigned)h[14]|((unsigned)h[15]<<16));
        char* zbase = lds + LZ + row * 1024;
        *(uint4*)(zbase + ((k0 * 2) ^ rswz))      = H0;
        *(uint4*)(zbase + ((k0 * 2 + 16) ^ rswz)) = H1;
    }
    __syncthreads();                           // ===== barrier A =====

    // ---- MFMA: 16 barrier-free k-steps (whole K resident) ----
    f32x4 acc = {0.f, 0.f, 0.f, 0.f};
    const int code = wu * 16 + l15;
    const int swzB = (l15 & 7) << 4;           // == (code&7)<<4
    const char* za = lds + LZ + l15 * 1024;
    const char* ba = lds + LCB + code * 1024;
    #pragma unroll
    for (int s = 0; s < 16; ++s) {
        const int kb = (s * 64 + kq * 16) ^ swzB;
        const bf16x8 a = *(const bf16x8*)(za + kb);
        const bf16x8 b = *(const bf16x8*)(ba + kb);
        acc = MFMA16(a, b, acc, 0, 0, 0);
    }

    // ---- wave-local top-4 per row over this wave's 16 codes ----
    // acc[j] is row kq*4+j, code `code`. 4-pass min-with-exclusion over the
    // 16-lane (fixed kq) group; results uniform across the group.
    float* twv = (float*)(lds + LTWV);
    int*   twi = (int*)(lds + LTWI);
    const float cnv = cnL[code];
    #pragma unroll
    for (int j = 0; j < 4; ++j) {
        float vv = cnv - 2.f * acc[j];
        int   vi = code;
        const int row = kq * 4 + j;
        #pragma unroll
        for (int t = 0; t < 4; ++t) {
            float mv = vv; int mi = vi;
            #pragma unroll
            for (int m = 1; m < 16; m <<= 1) {
                const float ov = __shfl_xor(mv, m, 64);
                const int   oi = __shfl_xor(mi, m, 64);
                if (lexlt(ov, oi, mv, mi)) { mv = ov; mi = oi; }
            }
            if (l15 == 0) {
                twv[(wu * 16 + row) * 4 + t] = mv;
                twi[(wu * 16 + row) * 4 + t] = mi;
            }
            if (vi == mi) { vv = 3.4e38f; vi = 0x7fffffff; }  // exclude picked
        }
    }
    __syncthreads();                           // ===== barrier B =====

    // ---- cross-wave merge: 32 cands/row -> global top-4 ----
    int* kb2 = (int*)(lds + LKB2);
    {
        const int row = tid >> 5;              // 0..15
        const int c32 = tid & 31;              // wave=c32>>2, slot=c32&3
        float vv = twv[((c32 >> 2) * 16 + row) * 4 + (c32 & 3)];
        int   vi = twi[((c32 >> 2) * 16 + row) * 4 + (c32 & 3)];
        #pragma unroll
        for (int t = 0; t < 4; ++t) {
            float mv = vv; int mi = vi;
            #pragma unroll
            for (int m = 1; m < 32; m <<= 1) {
                const float ov = __shfl_xor(mv, m, 64);
                const int   oi = __shfl_xor(mi, m, 64);
                if (lexlt(ov, oi, mv, mi)) { mv = ov; mi = oi; }
            }
            if (c32 == 0) kb2[row * 4 + t] = mi;
            if (vi == mi) { vv = 3.4e38f; vi = 0x7fffffff; }
        }
    }
    __syncthreads();                           // ===== barrier C =====

    // ---- exact f32 refinement: 64 jobs (16 rows x 4 cands) x 8 lanes ----
    float* refd = (float*)(lds + LREFD);
    {
        const int job = tid >> 3;              // 0..63
        const int l8  = tid & 7;
        const int row = job >> 2;
        const int cand = kb2[row * 4 + (job & 3)];
        const float* zr = (row < 8) ? z + (size_t)(r0 + row) * D
                                    : zp + (size_t)(r0 + row - 8) * D;
        const float* cr = cb + (size_t)cand * D;
        float dot = 0.f;
        #pragma unroll
        for (int it = 0; it < 32; ++it) {
            const int col = l8 * 2 + it * 16;
            if (col < D) {
                const float2 a = *(const float2*)(zr + col);
                const float2 b = *(const float2*)(cr + col);
                dot = fmaf(a.x, b.x, fmaf(a.y, b.y, dot));
            }
        }
        dot += __shfl_xor(dot, 1, 64);
        dot += __shfl_xor(dot, 2, 64);
        dot += __shfl_xor(dot, 4, 64);
        if (l8 == 0) refd[job] = cnL[cand] - 2.f * dot;
    }
    __syncthreads();                           // ===== barrier D =====

    int* kbf = (int*)(lds + LKBF);
    if (tid < 16) {
        float bd = refd[tid * 4]; int bi = kb2[tid * 4];
        #pragma unroll
        for (int q = 1; q < 4; ++q) {
            const float d = refd[tid * 4 + q];
            const int   i = kb2[tid * 4 + q];
            if (lexlt(d, i, bd, bi)) { bd = d; bi = i; }
        }
        kbf[tid] = bi;
    }
    __syncthreads();                           // ===== barrier E =====

    // ---- fused gather: 8 output rows x 64 lanes ----
    {
        const int grow = wu;                   // 0..7
        const int kz   = kbf[grow];
        const int kzp2 = kbf[8 + grow];
        const int pp   = pos[r0 + grow];
        const float* ra = cb + (size_t)kz * D;
        const float* rb = cb + (size_t)kzp2 * D;
        const float* rp = ph + (size_t)pp * D;
        float* ro = out + (size_t)(r0 + grow) * D;
        #pragma unroll
        for (int q = 0; q < 4; ++q) {
            const int col = lane * 8 + q * 2;
            if (col < D) {
                const float2 a = *(const float2*)(ra + col);
                const float2 b = *(const float2*)(rb + col);
                const float2 p = *(const float2*)(rp + col);
                float2 o; o.x = a.x + b.x + p.x; o.y = a.y + b.y + p.y;
                *(float2*)(ro + col) = o;
            }
        }
    }
}

extern "C" void kernel_launch(void* const* d_in, const int* in_sizes, int n_in,
                              void* d_out, int out_size, void* d_ws, size_t ws_size,
                              hipStream_t stream) {
    const float* z  = (const float*)d_in[0];
    const float* zp = (const float*)d_in[1];
    const float* cb = (const float*)d_in[2];
    const float* ph = (const float*)d_in[3];
    const int*   pos = (const int*)d_in[4];
    float* out = (float*)d_out;

    fused_kernel<<<GRID, 512, 0, stream>>>(z, zp, cb, ph, pos, out);
}

// Round 13
// 45.762 us; speedup vs baseline: 1.1170x; 1.1170x over previous
//
#include <hip/hip_runtime.h>

// PhraseModel: two VQ argmins (z, z_pre vs codebook) + phrase gather + sum.
// Round 13: r12's minimal-phase skeleton + two structural fixes:
//  (1) codebook in REGISTERS, wave-private (coalesced loads, no staging
//      barrier, block reads cb exactly once);
//  (2) LDS ~21KB -> 2 blocks/CU (overlap partner for every stall).
// Ranking: plain-bf16 MFMA (d2 err sigma ~0.07); exact-f32 top-4 refine
// per row decides (r12-proven epilogue, absmax 0). cnorm exact f32 from
// the same loads. Gather fused.

#define BHALF 4096
#define D 510
#define GRID 512                  // 8 output rows per block

using f32x4  = __attribute__((ext_vector_type(4))) float;
using bf16x8 = __attribute__((ext_vector_type(8))) short;

__device__ __forceinline__ unsigned short f2bf(float f) {
    union { float f; unsigned int u; } v; v.f = f;
    return (unsigned short)((v.u + 0x7FFFu + ((v.u >> 16) & 1u)) >> 16); // RTNE
}
__device__ __forceinline__ bool lexlt(float va, int ia, float vb, int ib) {
    return va < vb || (va == vb && ia < ib);
}
#define MFMA16 __builtin_amdgcn_mfma_f32_16x16x32_bf16

// LDS layout (bytes):
//   z    @0     : 16 rows x 1024B bf16 (swizzled: byte (k*2)^((row&7)<<4))
//   cn   @16384 : 128 f32 (exact ||c||^2)
//   twv  @16896 : [8][16][4] f32   wave-local top-4 values
//   twi  @18944 : [8][16][4] int   indices
//   kb2  @20992 : [16][4] int      global top-4 per row
//   refd @21248 : [64] f32         exact d2 of candidates
//   kbf  @21504 : [16] int         winner per row
#define LZ    0
#define LCN   16384
#define LTWV  16896
#define LTWI  18944
#define LKB2  20992
#define LREFD 21248
#define LKBF  21504
#define LDSZ  21568

__launch_bounds__(512, 4)
__global__ void fused_kernel(const float* __restrict__ z,
                             const float* __restrict__ zp,
                             const float* __restrict__ cb,
                             const float* __restrict__ ph,
                             const int* __restrict__ pos,
                             float* __restrict__ out) {
    __shared__ __align__(1024) char lds[LDSZ];

    const int tid  = threadIdx.x;
    const int lane = tid & 63;
    const int wu   = __builtin_amdgcn_readfirstlane(tid >> 6); // 0..7
    const int l15  = lane & 15;
    const int kq   = lane >> 4;          // 0..3
    const int r0   = blockIdx.x * 8;     // first output row
    const int code = wu * 16 + l15;      // this lane's code (B-frag column)

    float* cnL = (float*)(lds + LCN);

    // ---- stage z: 16 rows (8 z + 8 zp) -> LDS bf16, swizzled ----
    {
        const int row  = tid >> 5;             // 0..15
        const int k0   = (tid & 31) * 16;      // 0..496
        const int rswz = (row & 7) << 4;
        const float* src = (row < 8) ? z + (size_t)(r0 + row) * D
                                     : zp + (size_t)(r0 + row - 8) * D;
        float v[16];
        #pragma unroll
        for (int p = 0; p < 8; ++p) {
            const int col = k0 + 2 * p;
            const float2 t2 = (col < D) ? *(const float2*)(src + col)
                                        : make_float2(0.f, 0.f);
            v[2 * p] = t2.x; v[2 * p + 1] = t2.y;
        }
        unsigned short h[16];
        #pragma unroll
        for (int j = 0; j < 16; ++j) h[j] = f2bf(v[j]);
        uint4 H0 = make_uint4((unsigned)h[0]|((unsigned)h[1]<<16),
                              (unsigned)h[2]|((unsigned)h[3]<<16),
                              (unsigned)h[4]|((unsigned)h[5]<<16),
                              (unsigned)h[6]|((unsigned)h[7]<<16));
        uint4 H1 = make_uint4((unsigned)h[8]|((unsigned)h[9]<<16),
                              (unsigned)h[10]|((unsigned)h[11]<<16),
                              (unsigned)h[12]|((unsigned)h[13]<<16),
                              (unsigned)h[14]|((unsigned)h[15]<<16));
        char* zbase = lds + LZ + row * 1024;
        *(uint4*)(zbase + ((k0 * 2) ^ rswz))      = H0;
        *(uint4*)(zbase + ((k0 * 2 + 16) ^ rswz)) = H1;
    }

    // ---- B: wave-private codebook slab -> registers (bf16), exact cn ----
    // Lane (l15,kq): code row `code`, k in [s*32+kq*8, +8) for s=0..15.
    // 4 kq-lanes of one code read 32B-contiguous groups -> coalesced.
    bf16x8 B[16];                              // 64 VGPRs, static indexing
    {
        const float* cg = cb + (size_t)code * D;
        float sq = 0.f;
        #pragma unroll
        for (int s = 0; s < 16; ++s) {
            const int k0 = s * 32 + kq * 8;
            float v[8];
            #pragma unroll
            for (int p = 0; p < 4; ++p) {
                const int col = k0 + 2 * p;
                const float2 t2 = (col < D) ? *(const float2*)(cg + col)
                                            : make_float2(0.f, 0.f);
                v[2 * p] = t2.x; v[2 * p + 1] = t2.y;
            }
            bf16x8 h;
            #pragma unroll
            for (int j = 0; j < 8; ++j) {
                sq = fmaf(v[j], v[j], sq);
                h[j] = (short)f2bf(v[j]);
            }
            B[s] = h;
        }
        sq += __shfl_xor(sq, 16, 64);          // reduce over kq
        sq += __shfl_xor(sq, 32, 64);
        if (kq == 0) cnL[code] = sq;           // exact f32 ||c||^2
    }
    __syncthreads();                           // ===== barrier A =====

    // ---- MFMA: 16 barrier-free k-steps (A from LDS, B from regs) ----
    f32x4 acc = {0.f, 0.f, 0.f, 0.f};
    const int swzA = (l15 & 7) << 4;
    const char* za = lds + LZ + l15 * 1024;    // z row l15
    #pragma unroll
    for (int s = 0; s < 16; ++s) {
        const int kb = (s * 64 + kq * 16) ^ swzA;
        const bf16x8 a = *(const bf16x8*)(za + kb);
        acc = MFMA16(a, B[s], acc, 0, 0, 0);
    }

    // ---- wave-local top-4 per row over this wave's 16 codes ----
    float* twv = (float*)(lds + LTWV);
    int*   twi = (int*)(lds + LTWI);
    const float cnv = cnL[code];
    #pragma unroll
    for (int j = 0; j < 4; ++j) {
        float vv = cnv - 2.f * acc[j];
        int   vi = code;
        const int row = kq * 4 + j;
        #pragma unroll
        for (int t = 0; t < 4; ++t) {
            float mv = vv; int mi = vi;
            #pragma unroll
            for (int m = 1; m < 16; m <<= 1) {
                const float ov = __shfl_xor(mv, m, 64);
                const int   oi = __shfl_xor(mi, m, 64);
                if (lexlt(ov, oi, mv, mi)) { mv = ov; mi = oi; }
            }
            if (l15 == 0) {
                twv[(wu * 16 + row) * 4 + t] = mv;
                twi[(wu * 16 + row) * 4 + t] = mi;
            }
            if (vi == mi) { vv = 3.4e38f; vi = 0x7fffffff; }  // exclude picked
        }
    }
    __syncthreads();                           // ===== barrier B =====

    // ---- cross-wave merge: 32 cands/row -> global top-4 ----
    int* kb2 = (int*)(lds + LKB2);
    {
        const int row = tid >> 5;              // 0..15
        const int c32 = tid & 31;              // wave=c32>>2, slot=c32&3
        float vv = twv[((c32 >> 2) * 16 + row) * 4 + (c32 & 3)];
        int   vi = twi[((c32 >> 2) * 16 + row) * 4 + (c32 & 3)];
        #pragma unroll
        for (int t = 0; t < 4; ++t) {
            float mv = vv; int mi = vi;
            #pragma unroll
            for (int m = 1; m < 32; m <<= 1) {
                const float ov = __shfl_xor(mv, m, 64);
                const int   oi = __shfl_xor(mi, m, 64);
                if (lexlt(ov, oi, mv, mi)) { mv = ov; mi = oi; }
            }
            if (c32 == 0) kb2[row * 4 + t] = mi;
            if (vi == mi) { vv = 3.4e38f; vi = 0x7fffffff; }
        }
    }
    __syncthreads();                           // ===== barrier C =====

    // ---- exact f32 refinement: 64 jobs (16 rows x 4 cands) x 8 lanes ----
    float* refd = (float*)(lds + LREFD);
    {
        const int job = tid >> 3;              // 0..63
        const int l8  = tid & 7;
        const int row = job >> 2;
        const int cand = kb2[row * 4 + (job & 3)];
        const float* zr = (row < 8) ? z + (size_t)(r0 + row) * D
                                    : zp + (size_t)(r0 + row - 8) * D;
        const float* cr = cb + (size_t)cand * D;
        float dot = 0.f;
        #pragma unroll
        for (int it = 0; it < 32; ++it) {
            const int col = l8 * 2 + it * 16;
            if (col < D) {
                const float2 a = *(const float2*)(zr + col);
                const float2 b = *(const float2*)(cr + col);
                dot = fmaf(a.x, b.x, fmaf(a.y, b.y, dot));
            }
        }
        dot += __shfl_xor(dot, 1, 64);
        dot += __shfl_xor(dot, 2, 64);
        dot += __shfl_xor(dot, 4, 64);
        if (l8 == 0) refd[job] = cnL[cand] - 2.f * dot;
    }
    __syncthreads();                           // ===== barrier D =====

    int* kbf = (int*)(lds + LKBF);
    if (tid < 16) {
        float bd = refd[tid * 4]; int bi = kb2[tid * 4];
        #pragma unroll
        for (int q = 1; q < 4; ++q) {
            const float d = refd[tid * 4 + q];
            const int   i = kb2[tid * 4 + q];
            if (lexlt(d, i, bd, bi)) { bd = d; bi = i; }
        }
        kbf[tid] = bi;
    }
    __syncthreads();                           // ===== barrier E =====

    // ---- fused gather: 8 output rows x 64 lanes ----
    {
        const int grow = wu;                   // 0..7
        const int kz   = kbf[grow];
        const int kzp2 = kbf[8 + grow];
        const int pp   = pos[r0 + grow];
        const float* ra = cb + (size_t)kz * D;
        const float* rb = cb + (size_t)kzp2 * D;
        const float* rp = ph + (size_t)pp * D;
        float* ro = out + (size_t)(r0 + grow) * D;
        #pragma unroll
        for (int q = 0; q < 4; ++q) {
            const int col = lane * 8 + q * 2;
            if (col < D) {
                const float2 a = *(const float2*)(ra + col);
                const float2 b = *(const float2*)(rb + col);
                const float2 p = *(const float2*)(rp + col);
                float2 o; o.x = a.x + b.x + p.x; o.y = a.y + b.y + p.y;
                *(float2*)(ro + col) = o;
            }
        }
    }
}

extern "C" void kernel_launch(void* const* d_in, const int* in_sizes, int n_in,
                              void* d_out, int out_size, void* d_ws, size_t ws_size,
                              hipStream_t stream) {
    const float* z  = (const float*)d_in[0];
    const float* zp = (const float*)d_in[1];
    const float* cb = (const float*)d_in[2];
    const float* ph = (const float*)d_in[3];
    const int*   pos = (const int*)d_in[4];
    float* out = (float*)d_out;

    fused_kernel<<<GRID, 512, 0, stream>>>(z, zp, cb, ph, pos, out);
}